// Round 1
// baseline (391.809 us; speedup 1.0000x reference)
//
#include <hip/hip_runtime.h>

#define N_OBJ 1024
#define D_F   512
#define DB_F  64
#define E_P   32768
#define H_F   1024

// ---------------- copy kernels ----------------
__global__ __launch_bounds__(256) void k_copy_bbox(const float4* __restrict__ src,
                                                   float4* __restrict__ dst, int n4) {
    int i = blockIdx.x * blockDim.x + threadIdx.x;
    int stride = gridDim.x * blockDim.x;
    for (; i < n4; i += stride) dst[i] = src[i];
}

__global__ __launch_bounds__(256) void k_pairs_out(const int* __restrict__ pairs,
                                                   float* __restrict__ dst, int n) {
    int i = blockIdx.x * blockDim.x + threadIdx.x;
    if (i < n) dst[i] = (float)pairs[i];
}

// ---------------- CSR build ----------------
__global__ __launch_bounds__(256) void k_hist(const int* __restrict__ pairs,
                                              int* __restrict__ counts) {
    int e = blockIdx.x * blockDim.x + threadIdx.x;
    if (e < E_P) atomicAdd(&counts[pairs[2 * e]], 1);
}

__global__ __launch_bounds__(256) void k_scan(const int* __restrict__ counts,
                                              int* __restrict__ offsets,
                                              int* __restrict__ cursor) {
    __shared__ int buf[2][256];
    int tid = threadIdx.x;
    int c[4];
    int s = 0;
    #pragma unroll
    for (int i = 0; i < 4; ++i) { c[i] = counts[tid * 4 + i]; s += c[i]; }
    buf[0][tid] = s;
    __syncthreads();
    int sel = 0;
    for (int d = 1; d < 256; d <<= 1) {
        int v = buf[sel][tid];
        if (tid >= d) v += buf[sel][tid - d];
        buf[sel ^ 1][tid] = v;
        sel ^= 1;
        __syncthreads();
    }
    int base = buf[sel][tid] - s;   // exclusive prefix over thread-chunks
    int run = base;
    #pragma unroll
    for (int i = 0; i < 4; ++i) {
        offsets[tid * 4 + i] = run;
        cursor[tid * 4 + i]  = run;
        run += c[i];
    }
    if (tid == 255) offsets[1024] = run;  // == E_P
}

__global__ __launch_bounds__(256) void k_scatter(const int* __restrict__ pairs,
                                                 int* __restrict__ cursor,
                                                 int* __restrict__ csr) {
    int e = blockIdx.x * blockDim.x + threadIdx.x;
    if (e < E_P) {
        int sidx = pairs[2 * e];
        int pos = atomicAdd(&cursor[sidx], 1);
        csr[pos] = e;
    }
}

// ---------------- generic 64x64 fp32 tile GEMM body ----------------
template <int K, int LDA, int LDB>
__device__ __forceinline__ void mm64(const float* __restrict__ A, const float* __restrict__ B,
                                     int m0, int n0, int tx, int ty, float acc[4][4]) {
    __shared__ float As[16][68];
    __shared__ float Bs[16][68];
    const int tid = threadIdx.x;
    const int arow = tid >> 2, acs = (tid & 3) * 4;
    const int brow = tid >> 4, bcs = (tid & 15) * 4;
    for (int k0 = 0; k0 < K; k0 += 16) {
        float4 av = *(const float4*)&A[(size_t)(m0 + arow) * LDA + k0 + acs];
        float4 bv = *(const float4*)&B[(size_t)(k0 + brow) * LDB + n0 + bcs];
        As[acs + 0][arow] = av.x;
        As[acs + 1][arow] = av.y;
        As[acs + 2][arow] = av.z;
        As[acs + 3][arow] = av.w;
        *(float4*)&Bs[brow][bcs] = bv;
        __syncthreads();
        #pragma unroll
        for (int k = 0; k < 16; ++k) {
            float4 a = *(const float4*)&As[k][ty * 4];
            float4 b = *(const float4*)&Bs[k][tx * 4];
            acc[0][0] += a.x * b.x; acc[0][1] += a.x * b.y; acc[0][2] += a.x * b.z; acc[0][3] += a.x * b.w;
            acc[1][0] += a.y * b.x; acc[1][1] += a.y * b.y; acc[1][2] += a.y * b.z; acc[1][3] += a.y * b.w;
            acc[2][0] += a.z * b.x; acc[2][1] += a.z * b.y; acc[2][2] += a.z * b.z; acc[2][3] += a.z * b.w;
            acc[3][0] += a.w * b.x; acc[3][1] += a.w * b.y; acc[3][2] += a.w * b.z; acc[3][3] += a.w * b.w;
        }
        __syncthreads();
    }
}

// P = feats @ W1[0:512], Q = feats @ W1[512:1024]   (z selects)
__global__ __launch_bounds__(256) void k_gemm_pq(const float* __restrict__ feats,
                                                 const float* __restrict__ W1,
                                                 float* __restrict__ P, float* __restrict__ Q) {
    int tid = threadIdx.x, tx = tid & 15, ty = tid >> 4;
    int n0 = blockIdx.x * 64, m0 = blockIdx.y * 64;
    const float* B = W1 + (size_t)blockIdx.z * (512 * 1024);
    float* C = blockIdx.z ? Q : P;
    float acc[4][4] = {};
    mm64<512, 512, 1024>(feats, B, m0, n0, tx, ty, acc);
    #pragma unroll
    for (int i = 0; i < 4; ++i) {
        float4 v = make_float4(acc[i][0], acc[i][1], acc[i][2], acc[i][3]);
        *(float4*)&C[(size_t)(m0 + ty * 4 + i) * 1024 + n0 + tx * 4] = v;
    }
}

// out_feats = (feats + HS@W2 + count*b2) / (1+count)
__global__ __launch_bounds__(256) void k_gemm_out(const float* __restrict__ HS,
                                                  const float* __restrict__ W2,
                                                  const float* __restrict__ feats,
                                                  const float* __restrict__ b2,
                                                  const int* __restrict__ counts,
                                                  float* __restrict__ out0) {
    int tid = threadIdx.x, tx = tid & 15, ty = tid >> 4;
    int n0 = blockIdx.x * 64, m0 = blockIdx.y * 64;
    float acc[4][4] = {};
    mm64<1024, 1024, 512>(HS, W2, m0, n0, tx, ty, acc);
    float4 b2v = *(const float4*)&b2[n0 + tx * 4];
    #pragma unroll
    for (int i = 0; i < 4; ++i) {
        int m = m0 + ty * 4 + i;
        float cnt = (float)counts[m];
        float inv = 1.0f / (1.0f + cnt);
        float4 fv = *(const float4*)&feats[(size_t)m * 512 + n0 + tx * 4];
        float4 v;
        v.x = (fv.x + acc[i][0] + cnt * b2v.x) * inv;
        v.y = (fv.y + acc[i][1] + cnt * b2v.y) * inv;
        v.z = (fv.z + acc[i][2] + cnt * b2v.z) * inv;
        v.w = (fv.w + acc[i][3] + cnt * b2v.w) * inv;
        *(float4*)&out0[(size_t)m * 512 + n0 + tx * 4] = v;
    }
}

// Per-segment: HS[n] = sum_{e in seg n} relu(P[n] + Q[obj_e] + bb_e @ W1c + b1)
__global__ __launch_bounds__(256) void k_segment(const int* __restrict__ csr,
                                                 const int* __restrict__ offsets,
                                                 const int* __restrict__ pairs,
                                                 const float* __restrict__ bb,
                                                 const float* __restrict__ W1,
                                                 const float* __restrict__ P,
                                                 const float* __restrict__ Q,
                                                 const float* __restrict__ b1,
                                                 float* __restrict__ HS) {
    const int n = blockIdx.x;
    const int tid = threadIdx.x;
    const int j0 = tid * 4;
    const int start = offsets[n], end = offsets[n + 1];
    const float* W1c = W1 + (size_t)1024 * 1024;  // rows 1024..1087 of W1
    __shared__ float bb_s[8][64];
    __shared__ int obj_s[8];
    float4 Pv  = *(const float4*)&P[(size_t)n * 1024 + j0];
    float4 b1v = *(const float4*)&b1[j0];
    const float bx = Pv.x + b1v.x, by = Pv.y + b1v.y, bz = Pv.z + b1v.z, bw = Pv.w + b1v.w;
    float hsx = 0.f, hsy = 0.f, hsz = 0.f, hsw = 0.f;

    for (int s = start; s < end; s += 8) {
        int batch = min(8, end - s);
        __syncthreads();
        if (tid < batch) {
            int e = csr[s + tid];
            obj_s[tid] = pairs[2 * e + 1];
        }
        for (int u = tid; u < batch * 16; u += 256) {  // 16 float4 per bb row
            int p = u >> 4, q = u & 15;
            int e = csr[s + p];
            int se = pairs[2 * e], ob = pairs[2 * e + 1];
            *(float4*)&bb_s[p][q * 4] =
                *(const float4*)&bb[((size_t)se * 1024 + (size_t)ob) * 64 + q * 4];
        }
        __syncthreads();

        float4 acc[8];
        #pragma unroll
        for (int p = 0; p < 8; ++p) acc[p] = make_float4(0.f, 0.f, 0.f, 0.f);

        #pragma unroll 8
        for (int k = 0; k < 64; ++k) {
            float4 w = *(const float4*)&W1c[(size_t)k * 1024 + j0];
            #pragma unroll
            for (int p = 0; p < 8; ++p) {
                float bbv = bb_s[p][k];
                acc[p].x += bbv * w.x;
                acc[p].y += bbv * w.y;
                acc[p].z += bbv * w.z;
                acc[p].w += bbv * w.w;
            }
        }
        for (int p = 0; p < batch; ++p) {
            float4 qv = *(const float4*)&Q[(size_t)obj_s[p] * 1024 + j0];
            hsx += fmaxf(bx + qv.x + acc[p].x, 0.f);
            hsy += fmaxf(by + qv.y + acc[p].y, 0.f);
            hsz += fmaxf(bz + qv.z + acc[p].z, 0.f);
            hsw += fmaxf(bw + qv.w + acc[p].w, 0.f);
        }
    }
    float4 out = make_float4(hsx, hsy, hsz, hsw);
    *(float4*)&HS[(size_t)n * 1024 + j0] = out;
}

extern "C" void kernel_launch(void* const* d_in, const int* in_sizes, int n_in,
                              void* d_out, int out_size, void* d_ws, size_t ws_size,
                              hipStream_t stream) {
    const float* feats = (const float*)d_in[0];
    const float* bb    = (const float*)d_in[1];
    const int*   pairs = (const int*)d_in[2];
    const float* W1    = (const float*)d_in[3];
    const float* b1    = (const float*)d_in[4];
    const float* W2    = (const float*)d_in[5];
    const float* b2    = (const float*)d_in[6];

    float* out        = (float*)d_out;
    float* out_feats  = out;                                   // 1024*512
    float* out_bb     = out + (size_t)N_OBJ * D_F;              // 1024*1024*64
    float* out_pairs  = out + (size_t)N_OBJ * D_F + (size_t)N_OBJ * N_OBJ * DB_F; // 65536

    char* w = (char*)d_ws;
    float* P  = (float*)w;  w += (size_t)N_OBJ * H_F * 4;
    float* Q  = (float*)w;  w += (size_t)N_OBJ * H_F * 4;
    float* HS = (float*)w;  w += (size_t)N_OBJ * H_F * 4;
    int* counts  = (int*)w; w += 1024 * 4;
    int* offsets = (int*)w; w += 1028 * 4;
    int* cursor  = (int*)w; w += 1024 * 4;
    int* csr     = (int*)w; w += (size_t)E_P * 4;

    hipMemsetAsync(counts, 0, 1024 * sizeof(int), stream);

    k_copy_bbox<<<4096, 256, 0, stream>>>((const float4*)bb, (float4*)out_bb,
                                          (N_OBJ * N_OBJ * DB_F) / 4);
    k_pairs_out<<<(2 * E_P + 255) / 256, 256, 0, stream>>>(pairs, out_pairs, 2 * E_P);
    k_hist<<<(E_P + 255) / 256, 256, 0, stream>>>(pairs, counts);
    k_scan<<<1, 256, 0, stream>>>(counts, offsets, cursor);
    k_scatter<<<(E_P + 255) / 256, 256, 0, stream>>>(pairs, cursor, csr);

    dim3 gpq(H_F / 64, N_OBJ / 64, 2);
    k_gemm_pq<<<gpq, 256, 0, stream>>>(feats, W1, P, Q);

    k_segment<<<N_OBJ, 256, 0, stream>>>(csr, offsets, pairs, bb, W1, P, Q, b1, HS);

    dim3 gout(D_F / 64, N_OBJ / 64, 1);
    k_gemm_out<<<gout, 256, 0, stream>>>(HS, W2, feats, b2, counts, out_feats);
}

// Round 2
// 350.784 us; speedup vs baseline: 1.1170x; 1.1170x over previous
//
#include <hip/hip_runtime.h>

#define N_OBJ 1024
#define D_F   512
#define DB_F  64
#define E_P   32768
#define H_F   1024

// copy split (float4 units): total = 1024*1024*64/4 = 16777216
#define CP_LEN1 6291456
#define CP_LEN2 6291456
#define CP_LEN3 4194304
#define CP_OFF1 0
#define CP_OFF2 (CP_OFF1 + CP_LEN1)
#define CP_OFF3 (CP_OFF2 + CP_LEN2)

#define PQ_GEMM_BLOCKS 512
#define PQ_COPY_BLOCKS 512
#define SEG_COPY_BLOCKS 768
#define OUT_GEMM_BLOCKS 128
#define OUT_COPY_BLOCKS 1024

__device__ __forceinline__ void copy_role(const float4* __restrict__ src,
                                          float4* __restrict__ dst,
                                          int off, int len, int nblocks, int cb) {
    int i = off + cb * 256 + threadIdx.x;
    int end = off + len;
    int stride = nblocks * 256;
    for (; i < end; i += stride) dst[i] = src[i];
}

// ---------------- pairs passthrough + histogram ----------------
__global__ __launch_bounds__(256) void k_pre(const int* __restrict__ pairs,
                                             float* __restrict__ out_pairs,
                                             int* __restrict__ counts) {
    int i = blockIdx.x * blockDim.x + threadIdx.x;
    if (i < 2 * E_P) out_pairs[i] = (float)pairs[i];
    if (i < E_P) atomicAdd(&counts[pairs[2 * i]], 1);
}

__global__ __launch_bounds__(256) void k_scan(const int* __restrict__ counts,
                                              int* __restrict__ offsets,
                                              int* __restrict__ cursor) {
    __shared__ int buf[2][256];
    int tid = threadIdx.x;
    int c[4];
    int s = 0;
    #pragma unroll
    for (int i = 0; i < 4; ++i) { c[i] = counts[tid * 4 + i]; s += c[i]; }
    buf[0][tid] = s;
    __syncthreads();
    int sel = 0;
    for (int d = 1; d < 256; d <<= 1) {
        int v = buf[sel][tid];
        if (tid >= d) v += buf[sel][tid - d];
        buf[sel ^ 1][tid] = v;
        sel ^= 1;
        __syncthreads();
    }
    int base = buf[sel][tid] - s;
    int run = base;
    #pragma unroll
    for (int i = 0; i < 4; ++i) {
        offsets[tid * 4 + i] = run;
        cursor[tid * 4 + i]  = run;
        run += c[i];
    }
    if (tid == 255) offsets[1024] = run;
}

__global__ __launch_bounds__(256) void k_scatter(const int* __restrict__ pairs,
                                                 int* __restrict__ cursor,
                                                 int* __restrict__ csr) {
    int e = blockIdx.x * blockDim.x + threadIdx.x;
    if (e < E_P) {
        int sidx = pairs[2 * e];
        int pos = atomicAdd(&cursor[sidx], 1);
        csr[pos] = e;
    }
}

// ---------------- generic 64x64 fp32 tile GEMM body ----------------
template <int K, int LDA, int LDB>
__device__ __forceinline__ void mm64(const float* __restrict__ A, const float* __restrict__ B,
                                     int m0, int n0, int tx, int ty, float acc[4][4]) {
    __shared__ float As[16][68];
    __shared__ float Bs[16][68];
    const int tid = threadIdx.x;
    const int arow = tid >> 2, acs = (tid & 3) * 4;
    const int brow = tid >> 4, bcs = (tid & 15) * 4;
    for (int k0 = 0; k0 < K; k0 += 16) {
        float4 av = *(const float4*)&A[(size_t)(m0 + arow) * LDA + k0 + acs];
        float4 bv = *(const float4*)&B[(size_t)(k0 + brow) * LDB + n0 + bcs];
        As[acs + 0][arow] = av.x;
        As[acs + 1][arow] = av.y;
        As[acs + 2][arow] = av.z;
        As[acs + 3][arow] = av.w;
        *(float4*)&Bs[brow][bcs] = bv;
        __syncthreads();
        #pragma unroll
        for (int k = 0; k < 16; ++k) {
            float4 a = *(const float4*)&As[k][ty * 4];
            float4 b = *(const float4*)&Bs[k][tx * 4];
            acc[0][0] += a.x * b.x; acc[0][1] += a.x * b.y; acc[0][2] += a.x * b.z; acc[0][3] += a.x * b.w;
            acc[1][0] += a.y * b.x; acc[1][1] += a.y * b.y; acc[1][2] += a.y * b.z; acc[1][3] += a.y * b.w;
            acc[2][0] += a.z * b.x; acc[2][1] += a.z * b.y; acc[2][2] += a.z * b.z; acc[2][3] += a.z * b.w;
            acc[3][0] += a.w * b.x; acc[3][1] += a.w * b.y; acc[3][2] += a.w * b.z; acc[3][3] += a.w * b.w;
        }
        __syncthreads();
    }
}

// P = feats @ W1[0:512], Q = feats @ W1[512:1024]; plus copy role
__global__ __launch_bounds__(256) void k_gemm_pq(const float* __restrict__ feats,
                                                 const float* __restrict__ W1,
                                                 float* __restrict__ P, float* __restrict__ Q,
                                                 const float4* __restrict__ csrc,
                                                 float4* __restrict__ cdst) {
    if (blockIdx.x >= PQ_GEMM_BLOCKS) {
        copy_role(csrc, cdst, CP_OFF1, CP_LEN1, PQ_COPY_BLOCKS, blockIdx.x - PQ_GEMM_BLOCKS);
        return;
    }
    int g = blockIdx.x;
    int z = g >> 8;
    int rem = g & 255;
    int m0 = (rem >> 4) * 64, n0 = (rem & 15) * 64;
    int tid = threadIdx.x, tx = tid & 15, ty = tid >> 4;
    const float* B = W1 + (size_t)z * (512 * 1024);
    float* C = z ? Q : P;
    float acc[4][4] = {};
    mm64<512, 512, 1024>(feats, B, m0, n0, tx, ty, acc);
    #pragma unroll
    for (int i = 0; i < 4; ++i) {
        float4 v = make_float4(acc[i][0], acc[i][1], acc[i][2], acc[i][3]);
        *(float4*)&C[(size_t)(m0 + ty * 4 + i) * 1024 + n0 + tx * 4] = v;
    }
}

// out_feats = (feats + HS@W2 + count*b2) / (1+count); plus copy role
__global__ __launch_bounds__(256) void k_gemm_out(const float* __restrict__ HS,
                                                  const float* __restrict__ W2,
                                                  const float* __restrict__ feats,
                                                  const float* __restrict__ b2,
                                                  const int* __restrict__ counts,
                                                  float* __restrict__ out0,
                                                  const float4* __restrict__ csrc,
                                                  float4* __restrict__ cdst) {
    if (blockIdx.x >= OUT_GEMM_BLOCKS) {
        copy_role(csrc, cdst, CP_OFF3, CP_LEN3, OUT_COPY_BLOCKS, blockIdx.x - OUT_GEMM_BLOCKS);
        return;
    }
    int g = blockIdx.x;
    int m0 = (g >> 3) * 64, n0 = (g & 7) * 64;
    int tid = threadIdx.x, tx = tid & 15, ty = tid >> 4;
    float acc[4][4] = {};
    mm64<1024, 1024, 512>(HS, W2, m0, n0, tx, ty, acc);
    float4 b2v = *(const float4*)&b2[n0 + tx * 4];
    #pragma unroll
    for (int i = 0; i < 4; ++i) {
        int m = m0 + ty * 4 + i;
        float cnt = (float)counts[m];
        float inv = 1.0f / (1.0f + cnt);
        float4 fv = *(const float4*)&feats[(size_t)m * 512 + n0 + tx * 4];
        float4 v;
        v.x = (fv.x + acc[i][0] + cnt * b2v.x) * inv;
        v.y = (fv.y + acc[i][1] + cnt * b2v.y) * inv;
        v.z = (fv.z + acc[i][2] + cnt * b2v.z) * inv;
        v.w = (fv.w + acc[i][3] + cnt * b2v.w) * inv;
        *(float4*)&out0[(size_t)m * 512 + n0 + tx * 4] = v;
    }
}

// Per-segment: HS[n] = sum_{e in seg n} relu(P[n] + Q[obj_e] + bb_e @ W1c + b1)
// batch=16 pairs; plus copy role
__global__ __launch_bounds__(256) void k_segment(const int* __restrict__ csr,
                                                 const int* __restrict__ offsets,
                                                 const int* __restrict__ pairs,
                                                 const float* __restrict__ bb,
                                                 const float* __restrict__ W1,
                                                 const float* __restrict__ P,
                                                 const float* __restrict__ Q,
                                                 const float* __restrict__ b1,
                                                 float* __restrict__ HS,
                                                 const float4* __restrict__ csrc,
                                                 float4* __restrict__ cdst) {
    if (blockIdx.x >= N_OBJ) {
        copy_role(csrc, cdst, CP_OFF2, CP_LEN2, SEG_COPY_BLOCKS, blockIdx.x - N_OBJ);
        return;
    }
    const int n = blockIdx.x;
    const int tid = threadIdx.x;
    const int j0 = tid * 4;
    const int start = offsets[n], end = offsets[n + 1];
    const float* W1c = W1 + (size_t)1024 * 1024;
    __shared__ float bb_s[16][64];
    __shared__ int obj_s[16];
    float4 Pv  = *(const float4*)&P[(size_t)n * 1024 + j0];
    float4 b1v = *(const float4*)&b1[j0];
    const float bx = Pv.x + b1v.x, by = Pv.y + b1v.y, bz = Pv.z + b1v.z, bw = Pv.w + b1v.w;
    float hsx = 0.f, hsy = 0.f, hsz = 0.f, hsw = 0.f;

    for (int s = start; s < end; s += 16) {
        const int batch = min(16, end - s);
        __syncthreads();
        if (tid < 16) obj_s[tid] = (tid < batch) ? pairs[2 * csr[s + tid] + 1] : 0;
        {
            int p = tid >> 4, q = tid & 15;   // 256 threads = 16 rows x 16 float4
            float4 v = make_float4(0.f, 0.f, 0.f, 0.f);
            if (p < batch) {
                int e = csr[s + p];
                int se = pairs[2 * e], ob = pairs[2 * e + 1];
                v = *(const float4*)&bb[((size_t)se * 1024 + (size_t)ob) * 64 + q * 4];
            }
            *(float4*)&bb_s[p][q * 4] = v;
        }
        __syncthreads();

        float4 acc[16];
        #pragma unroll
        for (int p = 0; p < 16; ++p) acc[p] = make_float4(0.f, 0.f, 0.f, 0.f);

        #pragma unroll 4
        for (int k = 0; k < 64; ++k) {
            float4 w = *(const float4*)&W1c[(size_t)k * 1024 + j0];
            #pragma unroll
            for (int p = 0; p < 16; ++p) {
                float bbv = bb_s[p][k];
                acc[p].x += bbv * w.x;
                acc[p].y += bbv * w.y;
                acc[p].z += bbv * w.z;
                acc[p].w += bbv * w.w;
            }
        }
        for (int p = 0; p < batch; ++p) {
            float4 qv = *(const float4*)&Q[(size_t)obj_s[p] * 1024 + j0];
            hsx += fmaxf(bx + qv.x + acc[p].x, 0.f);
            hsy += fmaxf(by + qv.y + acc[p].y, 0.f);
            hsz += fmaxf(bz + qv.z + acc[p].z, 0.f);
            hsw += fmaxf(bw + qv.w + acc[p].w, 0.f);
        }
    }
    *(float4*)&HS[(size_t)n * 1024 + j0] = make_float4(hsx, hsy, hsz, hsw);
}

extern "C" void kernel_launch(void* const* d_in, const int* in_sizes, int n_in,
                              void* d_out, int out_size, void* d_ws, size_t ws_size,
                              hipStream_t stream) {
    const float* feats = (const float*)d_in[0];
    const float* bb    = (const float*)d_in[1];
    const int*   pairs = (const int*)d_in[2];
    const float* W1    = (const float*)d_in[3];
    const float* b1    = (const float*)d_in[4];
    const float* W2    = (const float*)d_in[5];
    const float* b2    = (const float*)d_in[6];

    float* out        = (float*)d_out;
    float* out_feats  = out;
    float* out_bb     = out + (size_t)N_OBJ * D_F;
    float* out_pairs  = out + (size_t)N_OBJ * D_F + (size_t)N_OBJ * N_OBJ * DB_F;

    char* w = (char*)d_ws;
    float* P  = (float*)w;  w += (size_t)N_OBJ * H_F * 4;
    float* Q  = (float*)w;  w += (size_t)N_OBJ * H_F * 4;
    float* HS = (float*)w;  w += (size_t)N_OBJ * H_F * 4;
    int* counts  = (int*)w; w += 1024 * 4;
    int* offsets = (int*)w; w += 1028 * 4;
    int* cursor  = (int*)w; w += 1024 * 4;
    int* csr     = (int*)w; w += (size_t)E_P * 4;

    const float4* cbb  = (const float4*)bb;
    float4*       cobb = (float4*)out_bb;

    hipMemsetAsync(counts, 0, 1024 * sizeof(int), stream);

    k_pre<<<(2 * E_P + 255) / 256, 256, 0, stream>>>(pairs, out_pairs, counts);
    k_scan<<<1, 256, 0, stream>>>(counts, offsets, cursor);
    k_scatter<<<(E_P + 255) / 256, 256, 0, stream>>>(pairs, cursor, csr);

    k_gemm_pq<<<PQ_GEMM_BLOCKS + PQ_COPY_BLOCKS, 256, 0, stream>>>(feats, W1, P, Q, cbb, cobb);

    k_segment<<<N_OBJ + SEG_COPY_BLOCKS, 256, 0, stream>>>(csr, offsets, pairs, bb, W1, P, Q, b1, HS,
                                                           cbb, cobb);

    k_gemm_out<<<OUT_GEMM_BLOCKS + OUT_COPY_BLOCKS, 256, 0, stream>>>(HS, W2, feats, b2, counts,
                                                                      out_feats, cbb, cobb);
}

// Round 3
// 288.170 us; speedup vs baseline: 1.3596x; 1.2173x over previous
//
#include <hip/hip_runtime.h>

#define N_OBJ 1024
#define D_F   512
#define DB_F  64
#define E_P   32768
#define H_F   1024

typedef float f32x4 __attribute__((ext_vector_type(4)));
typedef short bf16x8 __attribute__((ext_vector_type(8)));
typedef unsigned short u16x4 __attribute__((ext_vector_type(4)));

__device__ __forceinline__ unsigned short f2bf(float f) {
    unsigned u = __float_as_uint(f);
    u = u + 0x7FFFu + ((u >> 16) & 1u);   // RNE
    return (unsigned short)(u >> 16);
}

// ---- copy split (float4 units): total = 1024*1024*64/4 = 16777216 ----
#define CP_OFF_PREP 0
#define CP_LEN_PREP 1048576
#define CP_OFF_PRE  1048576
#define CP_LEN_PRE  1048576
#define CP_OFF_PQ   2097152
#define CP_LEN_PQ   2097152
#define CP_OFF_SEG  4194304
#define CP_LEN_SEG  6291456
#define CP_OFF_OUT  10485760
#define CP_LEN_OUT  6291456

#define PREP_JOBS 1856
#define PREP_COPY 512
#define PRE_JOBS  256
#define PRE_COPY  512
#define PQ_JOBS   512
#define PQ_COPY   768
#define SEG_JOBS  1024
#define SEG_COPY  2048
#define OUT_JOBS  128
#define OUT_COPY  2048

__device__ __forceinline__ void copy_role(const float4* __restrict__ src,
                                          float4* __restrict__ dst,
                                          int off, int len, int nblocks, int cb) {
    int i = off + cb * 256 + threadIdx.x;
    int end = off + len;
    int stride = nblocks * 256;
    for (; i < end; i += stride) dst[i] = src[i];
}

// ---------------- prep: transpose+convert weights, convert feats ----------------
__global__ __launch_bounds__(256) void k_prep(const float* __restrict__ W1,
                                              const float* __restrict__ W2,
                                              const float* __restrict__ feats,
                                              unsigned short* __restrict__ w1pqT,
                                              unsigned short* __restrict__ w1cT,
                                              unsigned short* __restrict__ w2T,
                                              unsigned short* __restrict__ featsb,
                                              const float4* __restrict__ csrc,
                                              float4* __restrict__ cdst) {
    int bid = blockIdx.x;
    if (bid >= PREP_JOBS) { copy_role(csrc, cdst, CP_OFF_PREP, CP_LEN_PREP, PREP_COPY, bid - PREP_JOBS); return; }
    int tid = threadIdx.x;
    if (bid >= 1600) {  // featsb straight convert: 256 blocks x 2048 elems
        int base = (bid - 1600) * 2048 + tid * 8;
        float4 v0 = *(const float4*)&feats[base];
        float4 v1 = *(const float4*)&feats[base + 4];
        u16x4 o0 = { f2bf(v0.x), f2bf(v0.y), f2bf(v0.z), f2bf(v0.w) };
        u16x4 o1 = { f2bf(v1.x), f2bf(v1.y), f2bf(v1.z), f2bf(v1.w) };
        *(u16x4*)&featsb[base] = o0;
        *(u16x4*)&featsb[base + 4] = o1;
        return;
    }
    const float* in; unsigned short* out;
    int LDI, LDO, r0, c0, nbase, kbase;
    if (bid < 1024) {            // W1[0:1024] -> w1pqT [2048][512]
        int t = bid; r0 = (t >> 5) * 32; c0 = (t & 31) * 32;
        in = W1; LDI = 1024; out = w1pqT; LDO = 512;
        nbase = c0 + (r0 >= 512 ? 1024 : 0); kbase = r0 & 511;
    } else if (bid < 1088) {     // W1[1024:1088] -> w1cT [1024][64]
        int t = bid - 1024; r0 = 1024 + (t >> 5) * 32; c0 = (t & 31) * 32;
        in = W1; LDI = 1024; out = w1cT; LDO = 64;
        nbase = c0; kbase = r0 - 1024;
    } else {                     // W2 [1024][512] -> w2T [512][1024]
        int t = bid - 1088; r0 = (t >> 4) * 32; c0 = (t & 15) * 32;
        in = W2; LDI = 512; out = w2T; LDO = 1024;
        nbase = c0; kbase = r0;
    }
    __shared__ float lds[32][33];
    int ti = tid >> 3, tj = (tid & 7) * 4;
    float4 v = *(const float4*)&in[(size_t)(r0 + ti) * LDI + c0 + tj];
    lds[ti][tj] = v.x; lds[ti][tj + 1] = v.y; lds[ti][tj + 2] = v.z; lds[ti][tj + 3] = v.w;
    __syncthreads();
    int oc = tid >> 3, oj = (tid & 7) * 4;
    u16x4 o = { f2bf(lds[oj][oc]), f2bf(lds[oj + 1][oc]), f2bf(lds[oj + 2][oc]), f2bf(lds[oj + 3][oc]) };
    *(u16x4*)&out[(size_t)(nbase + oc) * LDO + kbase + oj] = o;
}

// ---------------- pre: pairs passthrough + histogram ----------------
__global__ __launch_bounds__(256) void k_pre(const int* __restrict__ pairs,
                                             float* __restrict__ out_pairs,
                                             int* __restrict__ counts,
                                             const float4* __restrict__ csrc,
                                             float4* __restrict__ cdst) {
    int bid = blockIdx.x;
    if (bid >= PRE_JOBS) { copy_role(csrc, cdst, CP_OFF_PRE, CP_LEN_PRE, PRE_COPY, bid - PRE_JOBS); return; }
    int i = bid * 256 + threadIdx.x;
    if (i < 2 * E_P) out_pairs[i] = (float)pairs[i];
    if (i < E_P) atomicAdd(&counts[pairs[2 * i]], 1);
}

__global__ __launch_bounds__(256) void k_scan(const int* __restrict__ counts,
                                              int* __restrict__ offsets,
                                              int* __restrict__ cursor) {
    __shared__ int buf[2][256];
    int tid = threadIdx.x;
    int c[4]; int s = 0;
    #pragma unroll
    for (int i = 0; i < 4; ++i) { c[i] = counts[tid * 4 + i]; s += c[i]; }
    buf[0][tid] = s;
    __syncthreads();
    int sel = 0;
    for (int d = 1; d < 256; d <<= 1) {
        int v = buf[sel][tid];
        if (tid >= d) v += buf[sel][tid - d];
        buf[sel ^ 1][tid] = v;
        sel ^= 1;
        __syncthreads();
    }
    int base = buf[sel][tid] - s;
    int run = base;
    #pragma unroll
    for (int i = 0; i < 4; ++i) {
        offsets[tid * 4 + i] = run;
        cursor[tid * 4 + i]  = run;
        run += c[i];
    }
    if (tid == 255) offsets[1024] = run;
}

__global__ __launch_bounds__(256) void k_scatter(const int* __restrict__ pairs,
                                                 int* __restrict__ cursor,
                                                 int* __restrict__ csr) {
    int e = blockIdx.x * blockDim.x + threadIdx.x;
    if (e < E_P) {
        int sidx = pairs[2 * e];
        int pos = atomicAdd(&cursor[sidx], 1);
        csr[pos] = e;
    }
}

// ---------------- PQ: C(1024x2048) = featsb @ w1pqT^T ----------------
// col<1024 -> P (f32, +b1 folded); col>=1024 -> Q (f32)
__global__ __launch_bounds__(256) void k_pq(const unsigned short* __restrict__ featsb,
                                            const unsigned short* __restrict__ w1pqT,
                                            const float* __restrict__ b1,
                                            float* __restrict__ P, float* __restrict__ Q,
                                            const float4* __restrict__ csrc,
                                            float4* __restrict__ cdst) {
    int bid = blockIdx.x;
    if (bid >= PQ_JOBS) { copy_role(csrc, cdst, CP_OFF_PQ, CP_LEN_PQ, PQ_COPY, bid - PQ_JOBS); return; }
    int m0 = (bid >> 5) * 64, n0 = (bid & 31) * 64;
    int tid = threadIdx.x, w = tid >> 6, l = tid & 63;
    int ln = l & 15, kb = (l >> 4) * 8;
    int row = m0 + w * 16 + ln;
    f32x4 acc[4] = {};
    for (int k0 = 0; k0 < 512; k0 += 32) {
        bf16x8 a = *(const bf16x8*)&featsb[(size_t)row * 512 + k0 + kb];
        #pragma unroll
        for (int f = 0; f < 4; ++f) {
            bf16x8 b = *(const bf16x8*)&w1pqT[(size_t)(n0 + f * 16 + ln) * 512 + k0 + kb];
            acc[f] = __builtin_amdgcn_mfma_f32_16x16x32_bf16(a, b, acc[f], 0, 0, 0);
        }
    }
    int mr = m0 + w * 16 + (l >> 4) * 4;
    if (n0 < 1024) {
        #pragma unroll
        for (int f = 0; f < 4; ++f) {
            int n = n0 + f * 16 + ln;
            float b1v = b1[n];
            #pragma unroll
            for (int r = 0; r < 4; ++r)
                P[(size_t)(mr + r) * 1024 + n] = acc[f][r] + b1v;
        }
    } else {
        #pragma unroll
        for (int f = 0; f < 4; ++f) {
            int n = n0 - 1024 + f * 16 + ln;
            #pragma unroll
            for (int r = 0; r < 4; ++r)
                Q[(size_t)(mr + r) * 1024 + n] = acc[f][r];
        }
    }
}

// ---------------- segment: HSb[n] = sum_e relu(P'[n] + Q[obj_e] + bb_e@W1c) ----------------
__global__ __launch_bounds__(256) void k_seg(const int* __restrict__ csr,
                                             const int* __restrict__ offsets,
                                             const int* __restrict__ pairs,
                                             const float* __restrict__ bb,
                                             const unsigned short* __restrict__ w1cT,
                                             const float* __restrict__ P,
                                             const float* __restrict__ Q,
                                             unsigned short* __restrict__ HSb,
                                             const float4* __restrict__ csrc,
                                             float4* __restrict__ cdst) {
    int bid = blockIdx.x;
    if (bid >= SEG_JOBS) { copy_role(csrc, cdst, CP_OFF_SEG, CP_LEN_SEG, SEG_COPY, bid - SEG_JOBS); return; }
    const int seg = bid, tid = threadIdx.x, w = tid >> 6, l = tid & 63;
    const int ln = l & 15, g = l >> 4, kb = g * 8;
    const int n0 = w * 256;
    const int start = offsets[seg], end = offsets[seg + 1];

    float pv[16], hs[16];
    #pragma unroll
    for (int f = 0; f < 16; ++f) {
        pv[f] = P[(size_t)seg * 1024 + n0 + f * 16 + ln];
        hs[f] = 0.f;
    }

    for (int s = start; s < end; s += 16) {
        int batch = end - s; if (batch > 16) batch = 16;
        int idx = s + ln; if (idx > end - 1) idx = end - 1;
        int e = csr[idx];
        int obj = pairs[2 * e + 1];
        const float* br = &bb[((size_t)seg * 1024 + (size_t)obj) * 64];
        float4 a0 = *(const float4*)&br[kb];
        float4 a1 = *(const float4*)&br[kb + 4];
        float4 a2 = *(const float4*)&br[32 + kb];
        float4 a3 = *(const float4*)&br[32 + kb + 4];
        bf16x8 A0, A1;
        A0[0] = (short)f2bf(a0.x); A0[1] = (short)f2bf(a0.y); A0[2] = (short)f2bf(a0.z); A0[3] = (short)f2bf(a0.w);
        A0[4] = (short)f2bf(a1.x); A0[5] = (short)f2bf(a1.y); A0[6] = (short)f2bf(a1.z); A0[7] = (short)f2bf(a1.w);
        A1[0] = (short)f2bf(a2.x); A1[1] = (short)f2bf(a2.y); A1[2] = (short)f2bf(a2.z); A1[3] = (short)f2bf(a2.w);
        A1[4] = (short)f2bf(a3.x); A1[5] = (short)f2bf(a3.y); A1[6] = (short)f2bf(a3.z); A1[7] = (short)f2bf(a3.w);

        int ra0 = __shfl(obj, g * 4 + 0);
        int ra1 = __shfl(obj, g * 4 + 1);
        int ra2 = __shfl(obj, g * 4 + 2);
        int ra3 = __shfl(obj, g * 4 + 3);
        bool v0 = (g * 4 + 0) < batch;
        bool v1 = (g * 4 + 1) < batch;
        bool v2 = (g * 4 + 2) < batch;
        bool v3 = (g * 4 + 3) < batch;

        #pragma unroll
        for (int f = 0; f < 16; ++f) {
            const unsigned short* wr = &w1cT[(size_t)(n0 + f * 16 + ln) * 64];
            bf16x8 b0 = *(const bf16x8*)&wr[kb];
            bf16x8 b1 = *(const bf16x8*)&wr[32 + kb];
            f32x4 d = {0.f, 0.f, 0.f, 0.f};
            d = __builtin_amdgcn_mfma_f32_16x16x32_bf16(A0, b0, d, 0, 0, 0);
            d = __builtin_amdgcn_mfma_f32_16x16x32_bf16(A1, b1, d, 0, 0, 0);
            int col = n0 + f * 16 + ln;
            float q0 = Q[(size_t)ra0 * 1024 + col];
            float q1 = Q[(size_t)ra1 * 1024 + col];
            float q2 = Q[(size_t)ra2 * 1024 + col];
            float q3 = Q[(size_t)ra3 * 1024 + col];
            float t0 = d[0] + pv[f] + q0;
            float t1 = d[1] + pv[f] + q1;
            float t2 = d[2] + pv[f] + q2;
            float t3 = d[3] + pv[f] + q3;
            hs[f] += v0 ? fmaxf(t0, 0.f) : 0.f;
            hs[f] += v1 ? fmaxf(t1, 0.f) : 0.f;
            hs[f] += v2 ? fmaxf(t2, 0.f) : 0.f;
            hs[f] += v3 ? fmaxf(t3, 0.f) : 0.f;
        }
    }

    #pragma unroll
    for (int f = 0; f < 16; ++f) {
        float h = hs[f];
        h += __shfl_xor(h, 16);
        h += __shfl_xor(h, 32);
        if (l < 16) HSb[(size_t)seg * 1024 + n0 + f * 16 + l] = f2bf(h);
    }
}

// ---------------- out: (feats + HSb@W2 + cnt*b2)/(1+cnt) ----------------
__global__ __launch_bounds__(256) void k_out(const unsigned short* __restrict__ HSb,
                                             const unsigned short* __restrict__ w2T,
                                             const float* __restrict__ feats,
                                             const float* __restrict__ b2,
                                             const int* __restrict__ counts,
                                             float* __restrict__ out0,
                                             const float4* __restrict__ csrc,
                                             float4* __restrict__ cdst) {
    int bid = blockIdx.x;
    if (bid >= OUT_JOBS) { copy_role(csrc, cdst, CP_OFF_OUT, CP_LEN_OUT, OUT_COPY, bid - OUT_JOBS); return; }
    int m0 = (bid >> 3) * 64, n0 = (bid & 7) * 64;
    int tid = threadIdx.x, w = tid >> 6, l = tid & 63;
    int ln = l & 15, kb = (l >> 4) * 8;
    int row = m0 + w * 16 + ln;
    f32x4 acc[4] = {};
    for (int k0 = 0; k0 < 1024; k0 += 32) {
        bf16x8 a = *(const bf16x8*)&HSb[(size_t)row * 1024 + k0 + kb];
        #pragma unroll
        for (int f = 0; f < 4; ++f) {
            bf16x8 b = *(const bf16x8*)&w2T[(size_t)(n0 + f * 16 + ln) * 1024 + k0 + kb];
            acc[f] = __builtin_amdgcn_mfma_f32_16x16x32_bf16(a, b, acc[f], 0, 0, 0);
        }
    }
    int mr = m0 + w * 16 + (l >> 4) * 4;
    float cv[4], inv[4];
    #pragma unroll
    for (int r = 0; r < 4; ++r) {
        float c = (float)counts[mr + r];
        cv[r] = c;
        inv[r] = 1.0f / (1.0f + c);
    }
    #pragma unroll
    for (int f = 0; f < 4; ++f) {
        int n = n0 + f * 16 + ln;
        float b2v = b2[n];
        #pragma unroll
        for (int r = 0; r < 4; ++r) {
            float fv = feats[(size_t)(mr + r) * 512 + n];
            out0[(size_t)(mr + r) * 512 + n] = (fv + acc[f][r] + cv[r] * b2v) * inv[r];
        }
    }
}

extern "C" void kernel_launch(void* const* d_in, const int* in_sizes, int n_in,
                              void* d_out, int out_size, void* d_ws, size_t ws_size,
                              hipStream_t stream) {
    const float* feats = (const float*)d_in[0];
    const float* bb    = (const float*)d_in[1];
    const int*   pairs = (const int*)d_in[2];
    const float* W1    = (const float*)d_in[3];
    const float* b1    = (const float*)d_in[4];
    const float* W2    = (const float*)d_in[5];
    const float* b2    = (const float*)d_in[6];

    float* out        = (float*)d_out;
    float* out_feats  = out;
    float* out_bb     = out + (size_t)N_OBJ * D_F;
    float* out_pairs  = out + (size_t)N_OBJ * D_F + (size_t)N_OBJ * N_OBJ * DB_F;

    // workspace layout (<= ~12.3 MB, proven size)
    char* w = (char*)d_ws;
    unsigned short* featsb = (unsigned short*)w;                 // 1 MB  (dead after k_pq)
    unsigned short* HSb    = (unsigned short*)w;                 // 2 MB  (aliases featsb+w1pqT[0:1MB])
    unsigned short* w1pqT  = (unsigned short*)(w + (1u << 20));  // 2 MB
    unsigned short* w1cT   = (unsigned short*)(w + (3u << 20));  // 128 KB
    unsigned short* w2T    = (unsigned short*)(w + (3u << 20) + (128u << 10)); // 1 MB
    float* P = (float*)(w + (3u << 20) + (128u << 10) + (1u << 20));           // 4 MB
    float* Q = (float*)((char*)P + (4u << 20));                                 // 4 MB
    char* ints = (char*)Q + (4u << 20);
    int* counts  = (int*)ints;
    int* offsets = (int*)(ints + 4096);
    int* cursor  = (int*)(ints + 4096 + 4112);
    int* csr     = (int*)(ints + 4096 + 4112 + 4096);

    const float4* cbb  = (const float4*)bb;
    float4*       cobb = (float4*)out_bb;

    hipMemsetAsync(counts, 0, 1024 * sizeof(int), stream);

    k_prep<<<PREP_JOBS + PREP_COPY, 256, 0, stream>>>(W1, W2, feats, w1pqT, w1cT, w2T, featsb,
                                                      cbb, cobb);
    k_pre<<<PRE_JOBS + PRE_COPY, 256, 0, stream>>>(pairs, out_pairs, counts, cbb, cobb);
    k_scan<<<1, 256, 0, stream>>>(counts, offsets, cursor);
    k_scatter<<<(E_P + 255) / 256, 256, 0, stream>>>(pairs, cursor, csr);

    k_pq<<<PQ_JOBS + PQ_COPY, 256, 0, stream>>>(featsb, w1pqT, b1, P, Q, cbb, cobb);

    k_seg<<<SEG_JOBS + SEG_COPY, 256, 0, stream>>>(csr, offsets, pairs, bb, w1cT, P, Q, HSb,
                                                   cbb, cobb);

    k_out<<<OUT_JOBS + OUT_COPY, 256, 0, stream>>>(HSb, w2T, feats, b2, counts, out_feats,
                                                   cbb, cobb);
}

// Round 4
// 248.116 us; speedup vs baseline: 1.5791x; 1.1614x over previous
//
#include <hip/hip_runtime.h>

#define N_OBJ 1024
#define E_P   32768

typedef float f32x4 __attribute__((ext_vector_type(4)));
typedef short bf16x8 __attribute__((ext_vector_type(8)));
typedef unsigned short u16x4 __attribute__((ext_vector_type(4)));

__device__ __forceinline__ unsigned short f2bf(float f) {
    unsigned u = __float_as_uint(f);
    u = u + 0x7FFFu + ((u >> 16) & 1u);   // RNE
    return (unsigned short)(u >> 16);
}

// ---- copy split (float4 units): total = 1024*1024*64/4 = 16777216 ----
#define CP_OFF_PREP 0
#define CP_LEN_PREP 2097152
#define CP_OFF_PRE  (CP_OFF_PREP + CP_LEN_PREP)
#define CP_LEN_PRE  1048576
#define CP_OFF_PQ   (CP_OFF_PRE + CP_LEN_PRE)
#define CP_LEN_PQ   3145728
#define CP_OFF_SEG  (CP_OFF_PQ + CP_LEN_PQ)
#define CP_LEN_SEG  5242880
#define CP_OFF_OUT  (CP_OFF_SEG + CP_LEN_SEG)
#define CP_LEN_OUT  5242880

__device__ __forceinline__ void copy_role(const float4* __restrict__ src,
                                          float4* __restrict__ dst,
                                          int off, int len, int nblocks, int cb) {
    int i = off + cb * 256 + threadIdx.x;
    int end = off + len;
    int stride = nblocks * 256;
    for (; i < end; i += stride) dst[i] = src[i];
}

// ---------------- prep: transpose+convert weights, convert feats ----------------
// grid 2784: bid%3==2 -> copy (928 blocks); else job (1856)
__global__ __launch_bounds__(256) void k_prep(const float* __restrict__ W1,
                                              const float* __restrict__ W2,
                                              const float* __restrict__ feats,
                                              unsigned short* __restrict__ w1pqT,
                                              unsigned short* __restrict__ w1cT,
                                              unsigned short* __restrict__ w2T,
                                              unsigned short* __restrict__ featsb,
                                              const float4* __restrict__ csrc,
                                              float4* __restrict__ cdst) {
    int bid = blockIdx.x;
    if ((bid % 3) == 2) { copy_role(csrc, cdst, CP_OFF_PREP, CP_LEN_PREP, 928, bid / 3); return; }
    int job = (bid / 3) * 2 + (bid % 3);
    int tid = threadIdx.x;
    if (job >= 1600) {  // featsb straight convert: 256 blocks x 2048 elems
        int base = (job - 1600) * 2048 + tid * 8;
        float4 v0 = *(const float4*)&feats[base];
        float4 v1 = *(const float4*)&feats[base + 4];
        u16x4 o0 = { f2bf(v0.x), f2bf(v0.y), f2bf(v0.z), f2bf(v0.w) };
        u16x4 o1 = { f2bf(v1.x), f2bf(v1.y), f2bf(v1.z), f2bf(v1.w) };
        *(u16x4*)&featsb[base] = o0;
        *(u16x4*)&featsb[base + 4] = o1;
        return;
    }
    const float* in; unsigned short* out;
    int LDI, LDO, r0, c0, nbase, kbase;
    if (job < 1024) {            // W1[0:1024] -> w1pqT [2048][512]
        int t = job; r0 = (t >> 5) * 32; c0 = (t & 31) * 32;
        in = W1; LDI = 1024; out = w1pqT; LDO = 512;
        nbase = c0 + (r0 >= 512 ? 1024 : 0); kbase = r0 & 511;
    } else if (job < 1088) {     // W1[1024:1088] -> w1cT [1024][64]
        int t = job - 1024; r0 = 1024 + (t >> 5) * 32; c0 = (t & 31) * 32;
        in = W1; LDI = 1024; out = w1cT; LDO = 64;
        nbase = c0; kbase = r0 - 1024;
    } else {                     // W2 [1024][512] -> w2T [512][1024]
        int t = job - 1088; r0 = (t >> 4) * 32; c0 = (t & 15) * 32;
        in = W2; LDI = 512; out = w2T; LDO = 1024;
        nbase = c0; kbase = r0;
    }
    __shared__ float lds[32][33];
    int ti = tid >> 3, tj = (tid & 7) * 4;
    float4 v = *(const float4*)&in[(size_t)(r0 + ti) * LDI + c0 + tj];
    lds[ti][tj] = v.x; lds[ti][tj + 1] = v.y; lds[ti][tj + 2] = v.z; lds[ti][tj + 3] = v.w;
    __syncthreads();
    int oc = tid >> 3, oj = (tid & 7) * 4;
    u16x4 o = { f2bf(lds[oj][oc]), f2bf(lds[oj + 1][oc]), f2bf(lds[oj + 2][oc]), f2bf(lds[oj + 3][oc]) };
    *(u16x4*)&out[(size_t)(nbase + oc) * LDO + kbase + oj] = o;
}

// ---------------- pre: pairs passthrough + histogram ----------------
// grid 768: bid%3<2 -> copy (512); else job (256)
__global__ __launch_bounds__(256) void k_pre(const int* __restrict__ pairs,
                                             float* __restrict__ out_pairs,
                                             int* __restrict__ counts,
                                             const float4* __restrict__ csrc,
                                             float4* __restrict__ cdst) {
    int bid = blockIdx.x;
    if ((bid % 3) < 2) { copy_role(csrc, cdst, CP_OFF_PRE, CP_LEN_PRE, 512, (bid / 3) * 2 + (bid % 3)); return; }
    int i = (bid / 3) * 256 + threadIdx.x;
    if (i < 2 * E_P) out_pairs[i] = (float)pairs[i];
    if (i < E_P) atomicAdd(&counts[pairs[2 * i]], 1);
}

// ---------------- scan: offsets/cursor + batch records ----------------
__global__ __launch_bounds__(256) void k_scan(const int* __restrict__ counts,
                                              int* __restrict__ offsets,
                                              int* __restrict__ cursor,
                                              int* __restrict__ brec,
                                              int* __restrict__ bcnt) {
    __shared__ int buf[2][256];
    int tid = threadIdx.x;
    int c[4]; int s = 0;
    #pragma unroll
    for (int i = 0; i < 4; ++i) { c[i] = counts[tid * 4 + i]; s += c[i]; }
    buf[0][tid] = s;
    __syncthreads();
    int sel = 0;
    for (int d = 1; d < 256; d <<= 1) {
        int v = buf[sel][tid];
        if (tid >= d) v += buf[sel][tid - d];
        buf[sel ^ 1][tid] = v;
        sel ^= 1;
        __syncthreads();
    }
    int base = buf[sel][tid] - s;
    int run = base;
    #pragma unroll
    for (int i = 0; i < 4; ++i) {
        offsets[tid * 4 + i] = run;
        cursor[tid * 4 + i]  = run;
        run += c[i];
    }
    if (tid == 255) offsets[1024] = run;
    // phase 2: per-batch records (seg<<8 | k), one per 16-pair chunk
    int nb[4]; int t = 0;
    #pragma unroll
    for (int i = 0; i < 4; ++i) { nb[i] = (c[i] + 15) >> 4; t += nb[i]; }
    __syncthreads();
    buf[0][tid] = t;
    __syncthreads();
    sel = 0;
    for (int d = 1; d < 256; d <<= 1) {
        int v = buf[sel][tid];
        if (tid >= d) v += buf[sel][tid - d];
        buf[sel ^ 1][tid] = v;
        sel ^= 1;
        __syncthreads();
    }
    int bpos = buf[sel][tid] - t;
    #pragma unroll
    for (int i = 0; i < 4; ++i) {
        int seg = tid * 4 + i;
        for (int k = 0; k < nb[i]; ++k) brec[bpos++] = (seg << 8) | k;
    }
    if (tid == 255) bcnt[0] = bpos;
}

// ---------------- PQ GEMM (+ scatter role) ----------------
// grid 1664: bid>=1536 -> scatter (128); bid%3<2 -> copy (1024); else gemm (512)
__global__ __launch_bounds__(256) void k_pq(const unsigned short* __restrict__ featsb,
                                            const unsigned short* __restrict__ w1pqT,
                                            const float* __restrict__ b1,
                                            float* __restrict__ P, float* __restrict__ Q,
                                            const int* __restrict__ pairs,
                                            int* __restrict__ cursor,
                                            int* __restrict__ csr,
                                            const float4* __restrict__ csrc,
                                            float4* __restrict__ cdst) {
    int bid = blockIdx.x;
    if (bid >= 1536) {  // scatter role
        int e = (bid - 1536) * 256 + threadIdx.x;
        if (e < E_P) {
            int sidx = pairs[2 * e];
            int pos = atomicAdd(&cursor[sidx], 1);
            csr[pos] = e;
        }
        return;
    }
    if ((bid % 3) < 2) { copy_role(csrc, cdst, CP_OFF_PQ, CP_LEN_PQ, 1024, (bid / 3) * 2 + (bid % 3)); return; }
    int job = bid / 3;
    int m0 = (job >> 5) * 64, n0 = (job & 31) * 64;
    int tid = threadIdx.x, w = tid >> 6, l = tid & 63;
    int ln = l & 15, kb = (l >> 4) * 8;
    int row = m0 + w * 16 + ln;
    f32x4 acc[4] = {};
    for (int k0 = 0; k0 < 512; k0 += 32) {
        bf16x8 a = *(const bf16x8*)&featsb[(size_t)row * 512 + k0 + kb];
        #pragma unroll
        for (int f = 0; f < 4; ++f) {
            bf16x8 b = *(const bf16x8*)&w1pqT[(size_t)(n0 + f * 16 + ln) * 512 + k0 + kb];
            acc[f] = __builtin_amdgcn_mfma_f32_16x16x32_bf16(a, b, acc[f], 0, 0, 0);
        }
    }
    int mr = m0 + w * 16 + (l >> 4) * 4;
    if (n0 < 1024) {
        #pragma unroll
        for (int f = 0; f < 4; ++f) {
            int n = n0 + f * 16 + ln;
            float b1v = b1[n];
            #pragma unroll
            for (int r = 0; r < 4; ++r)
                P[(size_t)(mr + r) * 1024 + n] = acc[f][r] + b1v;
        }
    } else {
        #pragma unroll
        for (int f = 0; f < 4; ++f) {
            int n = n0 - 1024 + f * 16 + ln;
            #pragma unroll
            for (int r = 0; r < 4; ++r)
                Q[(size_t)(mr + r) * 1024 + n] = acc[f][r];
        }
    }
}

// ---------------- segment: one 16-pair batch per block, atomic accumulate ----------------
// grid 4608: bid%3==0 -> copy (1536); else batch job (3072 slots)
__global__ __launch_bounds__(256) void k_seg(const int* __restrict__ csr,
                                             const int* __restrict__ offsets,
                                             const int* __restrict__ brec,
                                             const int* __restrict__ bcnt,
                                             const int* __restrict__ pairs,
                                             const float* __restrict__ bb,
                                             const unsigned short* __restrict__ w1cT,
                                             const float* __restrict__ P,
                                             const float* __restrict__ Q,
                                             float* __restrict__ HS,
                                             const float4* __restrict__ csrc,
                                             float4* __restrict__ cdst) {
    int bid = blockIdx.x;
    if ((bid % 3) == 0) { copy_role(csrc, cdst, CP_OFF_SEG, CP_LEN_SEG, 1536, bid / 3); return; }
    int b = (bid / 3) * 2 + (bid % 3) - 1;
    if (b >= bcnt[0]) return;
    int rec = brec[b];
    int seg = rec >> 8, kchunk = rec & 255;
    int start = offsets[seg] + kchunk * 16;
    int end = offsets[seg + 1];
    int n = end - start; if (n > 16) n = 16;

    const int tid = threadIdx.x, w = tid >> 6, l = tid & 63;
    const int ln = l & 15, g = l >> 4, kb = g * 8;
    const int n0 = w * 256;

    int idx = start + ln; int last = end - 1; if (idx > last) idx = last;
    int e = csr[idx];
    int obj = pairs[2 * e + 1];
    const float* br = &bb[((size_t)seg * 1024 + (size_t)obj) * 64];
    float4 a0 = *(const float4*)&br[kb];
    float4 a1 = *(const float4*)&br[kb + 4];
    float4 a2 = *(const float4*)&br[32 + kb];
    float4 a3 = *(const float4*)&br[32 + kb + 4];
    bf16x8 A0, A1;
    A0[0] = (short)f2bf(a0.x); A0[1] = (short)f2bf(a0.y); A0[2] = (short)f2bf(a0.z); A0[3] = (short)f2bf(a0.w);
    A0[4] = (short)f2bf(a1.x); A0[5] = (short)f2bf(a1.y); A0[6] = (short)f2bf(a1.z); A0[7] = (short)f2bf(a1.w);
    A1[0] = (short)f2bf(a2.x); A1[1] = (short)f2bf(a2.y); A1[2] = (short)f2bf(a2.z); A1[3] = (short)f2bf(a2.w);
    A1[4] = (short)f2bf(a3.x); A1[5] = (short)f2bf(a3.y); A1[6] = (short)f2bf(a3.z); A1[7] = (short)f2bf(a3.w);

    int ra0 = __shfl(obj, g * 4 + 0);
    int ra1 = __shfl(obj, g * 4 + 1);
    int ra2 = __shfl(obj, g * 4 + 2);
    int ra3 = __shfl(obj, g * 4 + 3);
    bool v0 = (g * 4 + 0) < n;
    bool v1 = (g * 4 + 1) < n;
    bool v2 = (g * 4 + 2) < n;
    bool v3 = (g * 4 + 3) < n;

    float pv[16];
    #pragma unroll
    for (int f = 0; f < 16; ++f)
        pv[f] = P[(size_t)seg * 1024 + n0 + f * 16 + ln];

    #pragma unroll
    for (int f = 0; f < 16; ++f) {
        const unsigned short* wr = &w1cT[(size_t)(n0 + f * 16 + ln) * 64];
        bf16x8 b0 = *(const bf16x8*)&wr[kb];
        bf16x8 b1v = *(const bf16x8*)&wr[32 + kb];
        f32x4 d = {0.f, 0.f, 0.f, 0.f};
        d = __builtin_amdgcn_mfma_f32_16x16x32_bf16(A0, b0, d, 0, 0, 0);
        d = __builtin_amdgcn_mfma_f32_16x16x32_bf16(A1, b1v, d, 0, 0, 0);
        int col = n0 + f * 16 + ln;
        float q0 = Q[(size_t)ra0 * 1024 + col];
        float q1 = Q[(size_t)ra1 * 1024 + col];
        float q2 = Q[(size_t)ra2 * 1024 + col];
        float q3 = Q[(size_t)ra3 * 1024 + col];
        float h = 0.f;
        h += v0 ? fmaxf(d[0] + pv[f] + q0, 0.f) : 0.f;
        h += v1 ? fmaxf(d[1] + pv[f] + q1, 0.f) : 0.f;
        h += v2 ? fmaxf(d[2] + pv[f] + q2, 0.f) : 0.f;
        h += v3 ? fmaxf(d[3] + pv[f] + q3, 0.f) : 0.f;
        h += __shfl_xor(h, 16);
        h += __shfl_xor(h, 32);
        if (l < 16) atomicAdd(&HS[(size_t)seg * 1024 + n0 + f * 16 + l], h);
    }
}

// ---------------- out: (feats + HS@W2 + cnt*b2)/(1+cnt) ----------------
// grid 1664: bid%13==12 -> gemm (128); else copy (1536)
__global__ __launch_bounds__(256) void k_out(const float* __restrict__ HS,
                                             const unsigned short* __restrict__ w2T,
                                             const float* __restrict__ feats,
                                             const float* __restrict__ b2,
                                             const int* __restrict__ counts,
                                             float* __restrict__ out0,
                                             const float4* __restrict__ csrc,
                                             float4* __restrict__ cdst) {
    int bid = blockIdx.x;
    if ((bid % 13) != 12) { copy_role(csrc, cdst, CP_OFF_OUT, CP_LEN_OUT, 1536, (bid / 13) * 12 + (bid % 13)); return; }
    int job = bid / 13;
    int m0 = (job >> 3) * 64, n0 = (job & 7) * 64;
    int tid = threadIdx.x, w = tid >> 6, l = tid & 63;
    int ln = l & 15, kb = (l >> 4) * 8;
    int row = m0 + w * 16 + ln;
    f32x4 acc[4] = {};
    for (int k0 = 0; k0 < 1024; k0 += 32) {
        const float* hp = &HS[(size_t)row * 1024 + k0 + kb];
        float4 h0 = *(const float4*)&hp[0];
        float4 h1 = *(const float4*)&hp[4];
        bf16x8 a;
        a[0] = (short)f2bf(h0.x); a[1] = (short)f2bf(h0.y); a[2] = (short)f2bf(h0.z); a[3] = (short)f2bf(h0.w);
        a[4] = (short)f2bf(h1.x); a[5] = (short)f2bf(h1.y); a[6] = (short)f2bf(h1.z); a[7] = (short)f2bf(h1.w);
        #pragma unroll
        for (int f = 0; f < 4; ++f) {
            bf16x8 b = *(const bf16x8*)&w2T[(size_t)(n0 + f * 16 + ln) * 1024 + k0 + kb];
            acc[f] = __builtin_amdgcn_mfma_f32_16x16x32_bf16(a, b, acc[f], 0, 0, 0);
        }
    }
    int mr = m0 + w * 16 + (l >> 4) * 4;
    float cv[4], inv[4];
    #pragma unroll
    for (int r = 0; r < 4; ++r) {
        float c = (float)counts[mr + r];
        cv[r] = c;
        inv[r] = 1.0f / (1.0f + c);
    }
    #pragma unroll
    for (int f = 0; f < 4; ++f) {
        int n = n0 + f * 16 + ln;
        float b2v = b2[n];
        #pragma unroll
        for (int r = 0; r < 4; ++r) {
            float fv = feats[(size_t)(mr + r) * 512 + n];
            out0[(size_t)(mr + r) * 512 + n] = (fv + acc[f][r] + cv[r] * b2v) * inv[r];
        }
    }
}

extern "C" void kernel_launch(void* const* d_in, const int* in_sizes, int n_in,
                              void* d_out, int out_size, void* d_ws, size_t ws_size,
                              hipStream_t stream) {
    const float* feats = (const float*)d_in[0];
    const float* bb    = (const float*)d_in[1];
    const int*   pairs = (const int*)d_in[2];
    const float* W1    = (const float*)d_in[3];
    const float* b1    = (const float*)d_in[4];
    const float* W2    = (const float*)d_in[5];
    const float* b2    = (const float*)d_in[6];

    float* out        = (float*)d_out;
    float* out_feats  = out;
    float* out_bb     = out + (size_t)N_OBJ * 512;
    float* out_pairs  = out + (size_t)N_OBJ * 512 + (size_t)N_OBJ * N_OBJ * 64;

    // ---- workspace layout (~13.4 MB) ----
    // region A [0,4MB): featsb [0,1M), w1pqT [1M,3M)  -- dead after k_pq
    // HS (f32, 4MB) aliases region A (memset after k_pq)
    char* w = (char*)d_ws;
    unsigned short* featsb = (unsigned short*)w;
    unsigned short* w1pqT  = (unsigned short*)(w + (1u << 20));
    float*          HS     = (float*)w;
    unsigned short* w1cT   = (unsigned short*)(w + (4u << 20));
    unsigned short* w2T    = (unsigned short*)(w + (4u << 20) + (128u << 10));
    float* P = (float*)(w + (5u << 20) + (128u << 10));
    float* Q = (float*)(w + (9u << 20) + (128u << 10));
    char* ints = w + (13u << 20) + (128u << 10);
    int* counts  = (int*)ints;
    int* offsets = (int*)(ints + 4096);
    int* cursor  = (int*)(ints + 12288);
    int* csr     = (int*)(ints + 16384);
    int* brec    = (int*)(ints + 16384 + 131072);
    int* bcnt    = (int*)(ints + 16384 + 131072 + 16384);

    const float4* cbb  = (const float4*)bb;
    float4*       cobb = (float4*)out_bb;

    hipMemsetAsync(counts, 0, 4096, stream);

    k_prep<<<2784, 256, 0, stream>>>(W1, W2, feats, w1pqT, w1cT, w2T, featsb, cbb, cobb);
    k_pre<<<768, 256, 0, stream>>>(pairs, out_pairs, counts, cbb, cobb);
    k_scan<<<1, 256, 0, stream>>>(counts, offsets, cursor, brec, bcnt);
    k_pq<<<1664, 256, 0, stream>>>(featsb, w1pqT, b1, P, Q, pairs, cursor, csr, cbb, cobb);

    hipMemsetAsync(HS, 0, (size_t)N_OBJ * 1024 * sizeof(float), stream);

    k_seg<<<4608, 256, 0, stream>>>(csr, offsets, brec, bcnt, pairs, bb, w1cT, P, Q, HS, cbb, cobb);
    k_out<<<1664, 256, 0, stream>>>(HS, w2T, feats, b2, counts, out_feats, cbb, cobb);
}